// Round 5
// baseline (516.074 us; speedup 1.0000x reference)
//
#include <hip/hip_runtime.h>
#include <hip/hip_cooperative_groups.h>
#include <math.h>

namespace cg = cooperative_groups;

// Problem constants
#define B_     32
#define C_     512
#define HW_    56
#define PLANE  3136
#define PLANE4 784
#define GC_    128
#define L2_    64
#define HD_    64
#define EPS_   1e-5f
#define NBC    (B_*C_)    // 16384

typedef float floatx4 __attribute__((ext_vector_type(4)));

// ===========================================================================
// Fused cooperative kernel
// LDS union carving (floats):
//  Phase A: plane[0..3135], rp[3136..3359], cp[3360..3583]
//  Phase B: wl[0..1151], bl[1152..1279], red[4416..4425]
//  Phase C: plane[0..3135], a_h[3136..3191], a_w[3192..3247]
//  Phase E: yn[0..4351] (64 rows x 68), vbar[4352..4415], red[4416..4425]
// ===========================================================================
#define SMEM_F 4432

__global__ __launch_bounds__(256, 4) void k_fused(
    const float* __restrict__ x,
    const float* __restrict__ w3, const float* __restrict__ b3,
    const float* __restrict__ w5, const float* __restrict__ b5,
    const float* __restrict__ w7, const float* __restrict__ b7,
    const float* __restrict__ w9, const float* __restrict__ b9,
    const float* __restrict__ gnh_w, const float* __restrict__ gnh_b,
    const float* __restrict__ gnw_w, const float* __restrict__ gnw_b,
    const float* __restrict__ gn_w, const float* __restrict__ gn_b,
    const float* __restrict__ qw, const float* __restrict__ kw,
    const float* __restrict__ vw,
    float* __restrict__ xh, float* __restrict__ xw_,
    float* __restrict__ ah, float* __restrict__ aw,
    float* __restrict__ yy, float* __restrict__ ca,
    float* __restrict__ out)
{
    cg::grid_group grid = cg::this_grid();
    const int t    = threadIdx.x;
    const int blk  = blockIdx.x;
    const int nblk = gridDim.x;
    __shared__ float smem[SMEM_F];

    // ---------------- Phase A: row/col means per plane ----------------
    for (int bc = blk; bc < NBC; bc += nblk) {
        const floatx4* p4 = (const floatx4*)(x + (size_t)bc * PLANE);
        for (int f = t; f < PLANE4; f += 256) {
            floatx4 v = p4[f];
            int base = f * 4;
            smem[base]   = v.x; smem[base+1] = v.y;
            smem[base+2] = v.z; smem[base+3] = v.w;
        }
        __syncthreads();
        if (t < 224) {
            int r = t >> 2, q = t & 3;
            float s = 0.f;
            int base = r * HW_ + q * 14;
            #pragma unroll
            for (int i = 0; i < 14; i++) s += smem[base + i];
            smem[3136 + t] = s;
            float s2 = 0.f;
            int cb = q * 14 * HW_ + r;
            #pragma unroll
            for (int i = 0; i < 14; i++) s2 += smem[cb + i * HW_];
            smem[3360 + t] = s2;
        }
        __syncthreads();
        if (t < HW_) {
            float rs = smem[3136+4*t] + smem[3136+4*t+1] + smem[3136+4*t+2] + smem[3136+4*t+3];
            xh[(size_t)bc * HW_ + t] = rs * (1.0f / HW_);
            float cs = smem[3360+4*t] + smem[3360+4*t+1] + smem[3360+4*t+2] + smem[3360+4*t+3];
            xw_[(size_t)bc * HW_ + t] = cs * (1.0f / HW_);
        }
        __syncthreads();
    }
    grid.sync();

    // ---------------- Phase B: dwconv + GN + sigmoid (256 active blocks) ----
    if (blk < 256) {
        const int b     = blk >> 3;
        const int which = (blk & 7) >> 2;
        const int g     = blk & 3;

        const float* in  = (which ? xw_ : xh) + ((size_t)(b * C_ + g * GC_)) * HW_;
        float*       o   = (which ? aw  : ah) + ((size_t)(b * C_ + g * GC_)) * HW_;
        const float* gw  = (which ? gnw_w : gnh_w) + g * GC_;
        const float* gb  = (which ? gnw_b : gnh_b) + g * GC_;

        const float* wsel; const float* bsel; int ks;
        switch (g) {
            case 0:  wsel = w3; bsel = b3; ks = 3; break;
            case 1:  wsel = w5; bsel = b5; ks = 5; break;
            case 2:  wsel = w7; bsel = b7; ks = 7; break;
            default: wsel = w9; bsel = b9; ks = 9; break;
        }
        float* wl  = smem;           // 128*ks <= 1152
        float* bl  = smem + 1152;    // 128
        float* red = smem + 4416;    // 10

        const int nw = GC_ * ks;
        for (int i = t; i < nw; i += 256) wl[i] = wsel[i];
        if (t < GC_) bl[t] = bsel[t];
        __syncthreads();

        const int k2 = ks >> 1;
        float s = 0.f, s2 = 0.f;
        #pragma unroll
        for (int k = 0; k < 28; k++) {
            int idx = t + k * 256;
            int c = idx / HW_, l = idx - c * HW_;
            float a = bl[c];
            for (int tt = 0; tt < ks; tt++) {
                int pos = l + tt - k2;
                if (pos >= 0 && pos < HW_) a += wl[c * ks + tt] * in[c * HW_ + pos];
            }
            s += a; s2 += a * a;
        }
        #pragma unroll
        for (int off = 32; off > 0; off >>= 1) { s += __shfl_down(s, off); s2 += __shfl_down(s2, off); }
        int lane = t & 63, wid = t >> 6;
        if (lane == 0) { red[wid] = s; red[4 + wid] = s2; }
        __syncthreads();
        if (t == 0) {
            float S  = red[0] + red[1] + red[2] + red[3];
            float S2 = red[4] + red[5] + red[6] + red[7];
            float mean = S * (1.0f / (GC_ * HW_));
            float var  = S2 * (1.0f / (GC_ * HW_)) - mean * mean;
            red[8] = mean;
            red[9] = rsqrtf(var + EPS_);
        }
        __syncthreads();
        const float mean = red[8], rstd = red[9];

        #pragma unroll
        for (int k = 0; k < 28; k++) {
            int idx = t + k * 256;
            int c = idx / HW_, l = idx - c * HW_;
            float a = bl[c];
            for (int tt = 0; tt < ks; tt++) {
                int pos = l + tt - k2;
                if (pos >= 0 && pos < HW_) a += wl[c * ks + tt] * in[c * HW_ + pos];
            }
            float v = (a - mean) * rstd * gw[c] + gb[c];
            o[idx] = 1.0f / (1.0f + expf(-v));
        }
    }
    grid.sync();

    // ---------------- Phase C: gated 7x7 avg-pool -> y ----------------
    for (int bc = blk; bc < NBC; bc += nblk) {
        if (t < HW_) {
            smem[3136 + t] = ah[(size_t)bc * HW_ + t];
            smem[3192 + t] = aw[(size_t)bc * HW_ + t];
        }
        const floatx4* p4 = (const floatx4*)(x + (size_t)bc * PLANE);
        for (int f = t; f < PLANE4; f += 256) {
            floatx4 v = p4[f];
            int base = f * 4;
            smem[base]   = v.x; smem[base+1] = v.y;
            smem[base+2] = v.z; smem[base+3] = v.w;
        }
        __syncthreads();
        if (t < L2_) {
            int hh = t >> 3, ww = t & 7;
            float s = 0.f;
            #pragma unroll
            for (int i = 0; i < 7; i++) {
                float rsum = 0.f;
                int rbase = (7*hh + i) * HW_ + 7*ww;
                #pragma unroll
                for (int j = 0; j < 7; j++) rsum += smem[rbase + j] * smem[3192 + 7*ww + j];
                s += rsum * smem[3136 + 7*hh + i];
            }
            yy[(size_t)bc * L2_ + t] = s * (1.0f / 49.0f);
        }
        __syncthreads();
    }
    grid.sync();

    // ---------------- Phase E: GN(batch) + channel attention -> ca ----------
    if (blk < 256) {
        const int b = blk >> 3, h = blk & 7;
        float* yn   = smem;          // 64 x 68
        float* vbar = smem + 4352;   // 64
        float* red  = smem + 4416;   // 10

        {
            const floatx4* yb4 = (const floatx4*)(yy + (size_t)b * (C_ * L2_));
            float s = 0.f, s2 = 0.f;
            for (int i = t; i < (C_ * L2_ / 4); i += 256) {
                floatx4 v = yb4[i];
                s  += v.x + v.y + v.z + v.w;
                s2 += v.x*v.x + v.y*v.y + v.z*v.z + v.w*v.w;
            }
            #pragma unroll
            for (int off = 32; off > 0; off >>= 1) { s += __shfl_down(s, off); s2 += __shfl_down(s2, off); }
            int lane = t & 63, wid = t >> 6;
            if (lane == 0) { red[wid] = s; red[4 + wid] = s2; }
            __syncthreads();
            if (t == 0) {
                float S  = red[0] + red[1] + red[2] + red[3];
                float S2 = red[4] + red[5] + red[6] + red[7];
                float mean = S * (1.0f / (C_ * L2_));
                float var  = S2 * (1.0f / (C_ * L2_)) - mean * mean;
                red[8] = mean;
                red[9] = rsqrtf(var + EPS_);
            }
            __syncthreads();
        }
        const float mu = red[8], rstd = red[9];

        const floatx4* yp4 = (const floatx4*)(yy + ((size_t)(b * C_ + h * HD_)) * L2_);
        for (int f = t; f < 1024; f += 256) {
            int d = f >> 4, lb = (f & 15) << 2;
            int ch = h * HD_ + d;
            float gsc = gn_w[ch] * rstd;
            float gof = gn_b[ch] - mu * gsc;
            floatx4 v = yp4[f];
            yn[d*68 + lb]   = v.x * gsc + gof;
            yn[d*68 + lb+1] = v.y * gsc + gof;
            yn[d*68 + lb+2] = v.z * gsc + gof;
            yn[d*68 + lb+3] = v.w * gsc + gof;
        }
        __syncthreads();

        if (t < HD_) {
            int ch = h * HD_ + t;
            float s = 0.f;
            #pragma unroll
            for (int l = 0; l < L2_; l++) s += yn[t*68 + l];
            vbar[t] = s * (1.0f / L2_) * vw[ch];
        }
        __syncthreads();

        const int d = t >> 2, eb = t & 3;
        const int ch0 = h * HD_;
        float acc[16];
        #pragma unroll
        for (int i = 0; i < 16; i++) acc[i] = 0.f;
        #pragma unroll 4
        for (int lb = 0; lb < 16; lb++) {
            floatx4 qv = *(const floatx4*)&yn[d*68 + lb*4];
            #pragma unroll
            for (int i = 0; i < 16; i++) {
                floatx4 kv = *(const floatx4*)&yn[(eb + 4*i)*68 + lb*4];
                acc[i] += qv.x*kv.x + qv.y*kv.y + qv.z*kv.z + qv.w*kv.w;
            }
        }
        const float qg = qw[ch0 + d] * 0.125f;
        float m = -1e30f;
        #pragma unroll
        for (int i = 0; i < 16; i++) {
            acc[i] *= qg * kw[ch0 + eb + 4*i];
            m = fmaxf(m, acc[i]);
        }
        m = fmaxf(m, __shfl_xor(m, 1));
        m = fmaxf(m, __shfl_xor(m, 2));
        float s1 = 0.f, s2 = 0.f;
        #pragma unroll
        for (int i = 0; i < 16; i++) {
            float p = expf(acc[i] - m);
            s1 += p;
            s2 += p * vbar[eb + 4*i];
        }
        s1 += __shfl_xor(s1, 1); s2 += __shfl_xor(s2, 1);
        s1 += __shfl_xor(s1, 2); s2 += __shfl_xor(s2, 2);
        if (eb == 0) {
            float o = s2 / s1;
            ca[(size_t)b * C_ + ch0 + d] = 1.0f / (1.0f + expf(-o));
        }
    }
    grid.sync();

    // ---------------- Phase F: out = x * ah * aw * ca ----------------
    {
        const unsigned total4 = (unsigned)B_ * C_ * PLANE4;  // 12,845,056
        const unsigned stride = nblk * 256;
        const floatx4* px = (const floatx4*)x;
        floatx4*       po = (floatx4*)out;
        for (unsigned i = blk * 256 + t; i < total4; i += stride) {
            unsigned bc = i / PLANE4;
            unsigned r  = i - bc * PLANE4;
            unsigned hh = r / 14;
            unsigned jb = (r - hh * 14) * 4;

            floatx4 v  = px[i];
            floatx4 w4 = *(const floatx4*)&aw[bc * HW_ + jb];
            float   mm = ca[bc] * ah[bc * HW_ + hh];
            v.x *= mm * w4.x;
            v.y *= mm * w4.y;
            v.z *= mm * w4.z;
            v.w *= mm * w4.w;
            __builtin_nontemporal_store(v, &po[i]);
        }
    }
}

// ===========================================================================
// Fallback path: validated 5-kernel pipeline (R3, 173.5 us)
// ===========================================================================
__global__ __launch_bounds__(256) void k_means(const float* __restrict__ x,
                                               float* __restrict__ xh,
                                               float* __restrict__ xw) {
    const int bc = blockIdx.x;
    const int t  = threadIdx.x;
    __shared__ float lds[PLANE];
    __shared__ float rp[224];
    __shared__ float cp[224];

    const floatx4* p4 = (const floatx4*)(x + (size_t)bc * PLANE);
    for (int f = t; f < PLANE4; f += 256) {
        floatx4 v = p4[f];
        int base = f * 4;
        lds[base]   = v.x; lds[base+1] = v.y;
        lds[base+2] = v.z; lds[base+3] = v.w;
    }
    __syncthreads();
    if (t < 224) {
        int r = t >> 2, q = t & 3;
        float s = 0.f;
        int base = r * HW_ + q * 14;
        #pragma unroll
        for (int i = 0; i < 14; i++) s += lds[base + i];
        rp[t] = s;
        float s2 = 0.f;
        int cbase = q * 14 * HW_ + r;
        #pragma unroll
        for (int i = 0; i < 14; i++) s2 += lds[cbase + i * HW_];
        cp[t] = s2;
    }
    __syncthreads();
    if (t < HW_) {
        float rs = rp[4*t] + rp[4*t+1] + rp[4*t+2] + rp[4*t+3];
        xh[(size_t)bc * HW_ + t] = rs * (1.0f / HW_);
        float cs = cp[4*t] + cp[4*t+1] + cp[4*t+2] + cp[4*t+3];
        xw[(size_t)bc * HW_ + t] = cs * (1.0f / HW_);
    }
}

__global__ __launch_bounds__(256) void k_conv_gn_sig(
    const float* __restrict__ xh, const float* __restrict__ xw,
    const float* __restrict__ w3, const float* __restrict__ b3,
    const float* __restrict__ w5, const float* __restrict__ b5,
    const float* __restrict__ w7, const float* __restrict__ b7,
    const float* __restrict__ w9, const float* __restrict__ b9,
    const float* __restrict__ gnh_w, const float* __restrict__ gnh_b,
    const float* __restrict__ gnw_w, const float* __restrict__ gnw_b,
    float* __restrict__ ah, float* __restrict__ aw) {

    const int blk = blockIdx.x;
    const int b = blk >> 3;
    const int which = (blk & 7) >> 2;
    const int g = blk & 3;
    const int t = threadIdx.x;

    const float* in  = (which ? xw : xh) + ((size_t)(b * C_ + g * GC_)) * HW_;
    float*       out = (which ? aw : ah) + ((size_t)(b * C_ + g * GC_)) * HW_;
    const float* gw  = (which ? gnw_w : gnh_w) + g * GC_;
    const float* gb  = (which ? gnw_b : gnh_b) + g * GC_;

    const float* wsel; const float* bsel; int ks;
    switch (g) {
        case 0:  wsel = w3; bsel = b3; ks = 3; break;
        case 1:  wsel = w5; bsel = b5; ks = 5; break;
        case 2:  wsel = w7; bsel = b7; ks = 7; break;
        default: wsel = w9; bsel = b9; ks = 9; break;
    }

    __shared__ float lin[GC_ * HW_];
    __shared__ float wl[GC_ * 9];
    __shared__ float bl[GC_];
    __shared__ float red[10];

    for (int i = t; i < GC_ * HW_; i += 256) lin[i] = in[i];
    const int nw = GC_ * ks;
    for (int i = t; i < nw; i += 256) wl[i] = wsel[i];
    if (t < GC_) bl[t] = bsel[t];
    __syncthreads();

    const int k2 = ks >> 1;
    float acc[28];
    float s = 0.f, s2 = 0.f;
    #pragma unroll
    for (int k = 0; k < 28; k++) {
        int idx = t + k * 256;
        int c = idx / HW_, l = idx - c * HW_;
        float a = bl[c];
        for (int tt = 0; tt < ks; tt++) {
            int pos = l + tt - k2;
            if (pos >= 0 && pos < HW_) a += wl[c * ks + tt] * lin[c * HW_ + pos];
        }
        acc[k] = a;
        s += a; s2 += a * a;
    }
    #pragma unroll
    for (int o = 32; o > 0; o >>= 1) { s += __shfl_down(s, o); s2 += __shfl_down(s2, o); }
    int lane = t & 63, wid = t >> 6;
    if (lane == 0) { red[wid] = s; red[4 + wid] = s2; }
    __syncthreads();
    if (t == 0) {
        float S  = red[0] + red[1] + red[2] + red[3];
        float S2 = red[4] + red[5] + red[6] + red[7];
        float mean = S * (1.0f / (GC_ * HW_));
        float var  = S2 * (1.0f / (GC_ * HW_)) - mean * mean;
        red[8] = mean;
        red[9] = rsqrtf(var + EPS_);
    }
    __syncthreads();
    const float mean = red[8], rstd = red[9];

    #pragma unroll
    for (int k = 0; k < 28; k++) {
        int idx = t + k * 256;
        int c = idx / HW_;
        float v = (acc[k] - mean) * rstd * gw[c] + gb[c];
        out[idx] = 1.0f / (1.0f + expf(-v));
    }
}

__global__ __launch_bounds__(256) void k_pool(const float* __restrict__ x,
                                              const float* __restrict__ ah,
                                              const float* __restrict__ aw,
                                              float* __restrict__ y) {
    const int bc = blockIdx.x;
    const int t  = threadIdx.x;
    __shared__ float lds[PLANE];
    __shared__ float a_h[HW_];
    __shared__ float a_w[HW_];

    if (t < HW_) {
        a_h[t] = ah[(size_t)bc * HW_ + t];
        a_w[t] = aw[(size_t)bc * HW_ + t];
    }
    const floatx4* p4 = (const floatx4*)(x + (size_t)bc * PLANE);
    for (int f = t; f < PLANE4; f += 256) {
        floatx4 v = p4[f];
        int base = f * 4;
        lds[base]   = v.x; lds[base+1] = v.y;
        lds[base+2] = v.z; lds[base+3] = v.w;
    }
    __syncthreads();
    if (t < L2_) {
        int hh = t >> 3, ww = t & 7;
        float s = 0.f;
        #pragma unroll
        for (int i = 0; i < 7; i++) {
            float rsum = 0.f;
            int rbase = (7*hh + i) * HW_ + 7*ww;
            #pragma unroll
            for (int j = 0; j < 7; j++) rsum += lds[rbase + j] * a_w[7*ww + j];
            s += rsum * a_h[7*hh + i];
        }
        y[(size_t)bc * L2_ + t] = s * (1.0f / 49.0f);
    }
}

__global__ __launch_bounds__(256) void k_attn(const float* __restrict__ y,
                                              const float* __restrict__ gn_w,
                                              const float* __restrict__ gn_b,
                                              const float* __restrict__ qw,
                                              const float* __restrict__ kw,
                                              const float* __restrict__ vw,
                                              float* __restrict__ ca) {
    const int blk = blockIdx.x;
    const int b = blk >> 3, h = blk & 7;
    const int t = threadIdx.x;

    __shared__ float yn[HD_ * 68];
    __shared__ float vbar[HD_];
    __shared__ float red[10];

    {
        const floatx4* yb4 = (const floatx4*)(y + (size_t)b * (C_ * L2_));
        float s = 0.f, s2 = 0.f;
        for (int i = t; i < (C_ * L2_ / 4); i += 256) {
            floatx4 v = yb4[i];
            s  += v.x + v.y + v.z + v.w;
            s2 += v.x*v.x + v.y*v.y + v.z*v.z + v.w*v.w;
        }
        #pragma unroll
        for (int off = 32; off > 0; off >>= 1) { s += __shfl_down(s, off); s2 += __shfl_down(s2, off); }
        int lane = t & 63, wid = t >> 6;
        if (lane == 0) { red[wid] = s; red[4 + wid] = s2; }
        __syncthreads();
        if (t == 0) {
            float S  = red[0] + red[1] + red[2] + red[3];
            float S2 = red[4] + red[5] + red[6] + red[7];
            float mean = S * (1.0f / (C_ * L2_));
            float var  = S2 * (1.0f / (C_ * L2_)) - mean * mean;
            red[8] = mean;
            red[9] = rsqrtf(var + EPS_);
        }
        __syncthreads();
    }
    const float mu = red[8], rstd = red[9];

    const floatx4* yp4 = (const floatx4*)(y + ((size_t)(b * C_ + h * HD_)) * L2_);
    for (int f = t; f < 1024; f += 256) {
        int d = f >> 4, lb = (f & 15) << 2;
        int ch = h * HD_ + d;
        float gsc = gn_w[ch] * rstd;
        float gof = gn_b[ch] - mu * gsc;
        floatx4 v = yp4[f];
        yn[d*68 + lb]   = v.x * gsc + gof;
        yn[d*68 + lb+1] = v.y * gsc + gof;
        yn[d*68 + lb+2] = v.z * gsc + gof;
        yn[d*68 + lb+3] = v.w * gsc + gof;
    }
    __syncthreads();

    if (t < HD_) {
        int ch = h * HD_ + t;
        float s = 0.f;
        #pragma unroll
        for (int l = 0; l < L2_; l++) s += yn[t*68 + l];
        vbar[t] = s * (1.0f / L2_) * vw[ch];
    }
    __syncthreads();

    const int d = t >> 2, eb = t & 3;
    const int ch0 = h * HD_;
    float acc[16];
    #pragma unroll
    for (int i = 0; i < 16; i++) acc[i] = 0.f;
    #pragma unroll 4
    for (int lb = 0; lb < 16; lb++) {
        floatx4 qv = *(const floatx4*)&yn[d*68 + lb*4];
        #pragma unroll
        for (int i = 0; i < 16; i++) {
            floatx4 kv = *(const floatx4*)&yn[(eb + 4*i)*68 + lb*4];
            acc[i] += qv.x*kv.x + qv.y*kv.y + qv.z*kv.z + qv.w*kv.w;
        }
    }
    const float qg = qw[ch0 + d] * 0.125f;
    float m = -1e30f;
    #pragma unroll
    for (int i = 0; i < 16; i++) {
        acc[i] *= qg * kw[ch0 + eb + 4*i];
        m = fmaxf(m, acc[i]);
    }
    m = fmaxf(m, __shfl_xor(m, 1));
    m = fmaxf(m, __shfl_xor(m, 2));
    float s1 = 0.f, s2 = 0.f;
    #pragma unroll
    for (int i = 0; i < 16; i++) {
        float p = expf(acc[i] - m);
        s1 += p;
        s2 += p * vbar[eb + 4*i];
    }
    s1 += __shfl_xor(s1, 1); s2 += __shfl_xor(s2, 1);
    s1 += __shfl_xor(s1, 2); s2 += __shfl_xor(s2, 2);
    if (eb == 0) {
        float o = s2 / s1;
        ca[(size_t)b * C_ + ch0 + d] = 1.0f / (1.0f + expf(-o));
    }
}

__global__ __launch_bounds__(256) void k_out(const float* __restrict__ x,
                                             const float* __restrict__ ah,
                                             const float* __restrict__ aw,
                                             const float* __restrict__ ca,
                                             float* __restrict__ out) {
    const unsigned total4 = (unsigned)B_ * C_ * PLANE4;
    const unsigned stride = gridDim.x * blockDim.x;
    const floatx4* px = (const floatx4*)x;
    floatx4*       po = (floatx4*)out;

    for (unsigned i = blockIdx.x * blockDim.x + threadIdx.x; i < total4; i += stride) {
        unsigned bc = i / PLANE4;
        unsigned r  = i - bc * PLANE4;
        unsigned hh = r / 14;
        unsigned jb = (r - hh * 14) * 4;

        floatx4 v  = px[i];
        floatx4 w4 = *(const floatx4*)&aw[bc * HW_ + jb];
        float   m  = ca[bc] * ah[bc * HW_ + hh];
        v.x *= m * w4.x;
        v.y *= m * w4.y;
        v.z *= m * w4.z;
        v.w *= m * w4.w;
        __builtin_nontemporal_store(v, &po[i]);
    }
}

// ---------------------------------------------------------------------------
extern "C" void kernel_launch(void* const* d_in, const int* in_sizes, int n_in,
                              void* d_out, int out_size, void* d_ws, size_t ws_size,
                              hipStream_t stream) {
    const float* x     = (const float*)d_in[0];
    const float* w3    = (const float*)d_in[1];
    const float* b3    = (const float*)d_in[2];
    const float* w5    = (const float*)d_in[3];
    const float* b5    = (const float*)d_in[4];
    const float* w7    = (const float*)d_in[5];
    const float* b7    = (const float*)d_in[6];
    const float* w9    = (const float*)d_in[7];
    const float* b9    = (const float*)d_in[8];
    const float* gnh_w = (const float*)d_in[9];
    const float* gnh_b = (const float*)d_in[10];
    const float* gnw_w = (const float*)d_in[11];
    const float* gnw_b = (const float*)d_in[12];
    const float* gn_w  = (const float*)d_in[13];
    const float* gn_b  = (const float*)d_in[14];
    const float* qw    = (const float*)d_in[15];
    const float* kw    = (const float*)d_in[16];
    const float* vw    = (const float*)d_in[17];

    float* ws = (float*)d_ws;
    const size_t N_BC56 = (size_t)B_ * C_ * HW_;
    float* xh  = ws;
    float* xw_ = xh + N_BC56;
    float* ah  = xw_ + N_BC56;
    float* aw  = ah + N_BC56;
    float* yy  = aw + N_BC56;
    float* ca  = yy + (size_t)B_ * C_ * L2_;
    float* out = (float*)d_out;

    // Determine a safe cooperative grid size (deterministic host queries).
    int maxPerCU = 0;
    hipError_t qerr = hipOccupancyMaxActiveBlocksPerMultiprocessor(
        &maxPerCU, (const void*)k_fused, 256, 0);
    int numCU = 0;
    hipError_t derr = hipDeviceGetAttribute(&numCU, hipDeviceAttributeMultiprocessorCount, 0);
    int grid = 0;
    if (qerr == hipSuccess && derr == hipSuccess && maxPerCU > 0 && numCU > 0) {
        long cap = (long)maxPerCU * numCU;
        grid = (int)(cap < 1024 ? cap : 1024);
    }

    hipError_t lerr = hipErrorUnknown;
    if (grid >= 256) {
        void* args[] = {
            (void*)&x,
            (void*)&w3, (void*)&b3, (void*)&w5, (void*)&b5,
            (void*)&w7, (void*)&b7, (void*)&w9, (void*)&b9,
            (void*)&gnh_w, (void*)&gnh_b, (void*)&gnw_w, (void*)&gnw_b,
            (void*)&gn_w, (void*)&gn_b,
            (void*)&qw, (void*)&kw, (void*)&vw,
            (void*)&xh, (void*)&xw_, (void*)&ah, (void*)&aw,
            (void*)&yy, (void*)&ca, (void*)&out,
        };
        lerr = hipLaunchCooperativeKernel((void*)k_fused, dim3(grid), dim3(256),
                                          args, 0, stream);
    }

    if (lerr != hipSuccess) {
        // Fallback: validated 5-kernel pipeline.
        const int nbc = B_ * C_;
        k_means<<<nbc, 256, 0, stream>>>(x, xh, xw_);
        k_conv_gn_sig<<<B_ * 8, 256, 0, stream>>>(xh, xw_, w3, b3, w5, b5, w7, b7, w9, b9,
                                                  gnh_w, gnh_b, gnw_w, gnw_b, ah, aw);
        k_pool<<<nbc, 256, 0, stream>>>(x, ah, aw, yy);
        k_attn<<<B_ * 8, 256, 0, stream>>>(yy, gn_w, gn_b, qw, kw, vw, ca);
        k_out<<<2048, 256, 0, stream>>>(x, ah, aw, ca, out);
    }
}

// Round 6
// 349.148 us; speedup vs baseline: 1.4781x; 1.4781x over previous
//
#include <hip/hip_runtime.h>
#include <math.h>

// Problem constants
#define B_     32
#define C_     512
#define HW_    56
#define PLANE  3136
#define PLANE4 784
#define GC_    128
#define L2_    64
#define HD_    64
#define EPS_   1e-5f

typedef float floatx4 __attribute__((ext_vector_type(4)));

// ---------------------------------------------------------------------------
// K1: per-(b,c) plane -> row means (over W) = x_h, col means (over H) = x_w
//     block 0 additionally zeroes stats[0..63] (used by K3's atomics)
// ---------------------------------------------------------------------------
__global__ __launch_bounds__(256) void k_means(const float* __restrict__ x,
                                               float* __restrict__ xh,
                                               float* __restrict__ xw,
                                               float* __restrict__ stats) {
    const int bc = blockIdx.x;
    const int t  = threadIdx.x;
    __shared__ float lds[PLANE];
    __shared__ float rp[224];
    __shared__ float cp[224];

    if (bc == 0 && t < 2 * B_) stats[t] = 0.f;

    const floatx4* p4 = (const floatx4*)(x + (size_t)bc * PLANE);
    for (int f = t; f < PLANE4; f += 256) {
        floatx4 v = p4[f];
        int base = f * 4;
        lds[base]   = v.x; lds[base+1] = v.y;
        lds[base+2] = v.z; lds[base+3] = v.w;
    }
    __syncthreads();
    if (t < 224) {
        int r = t >> 2, q = t & 3;
        float s = 0.f;
        int base = r * HW_ + q * 14;
        #pragma unroll
        for (int i = 0; i < 14; i++) s += lds[base + i];
        rp[t] = s;
        float s2 = 0.f;
        int cbase = q * 14 * HW_ + r;
        #pragma unroll
        for (int i = 0; i < 14; i++) s2 += lds[cbase + i * HW_];
        cp[t] = s2;
    }
    __syncthreads();
    if (t < HW_) {
        float rs = rp[4*t] + rp[4*t+1] + rp[4*t+2] + rp[4*t+3];
        xh[(size_t)bc * HW_ + t] = rs * (1.0f / HW_);
        float cs = cp[4*t] + cp[4*t+1] + cp[4*t+2] + cp[4*t+3];
        xw[(size_t)bc * HW_ + t] = cs * (1.0f / HW_);
    }
}

// ---------------------------------------------------------------------------
// K2: per (b, group, {h|w}): depthwise conv1d + bias, GroupNorm, sigmoid
// ---------------------------------------------------------------------------
__global__ __launch_bounds__(256) void k_conv_gn_sig(
    const float* __restrict__ xh, const float* __restrict__ xw,
    const float* __restrict__ w3, const float* __restrict__ b3,
    const float* __restrict__ w5, const float* __restrict__ b5,
    const float* __restrict__ w7, const float* __restrict__ b7,
    const float* __restrict__ w9, const float* __restrict__ b9,
    const float* __restrict__ gnh_w, const float* __restrict__ gnh_b,
    const float* __restrict__ gnw_w, const float* __restrict__ gnw_b,
    float* __restrict__ ah, float* __restrict__ aw) {

    const int blk = blockIdx.x;
    const int b = blk >> 3;
    const int which = (blk & 7) >> 2;
    const int g = blk & 3;
    const int t = threadIdx.x;

    const float* in  = (which ? xw : xh) + ((size_t)(b * C_ + g * GC_)) * HW_;
    float*       out = (which ? aw : ah) + ((size_t)(b * C_ + g * GC_)) * HW_;
    const float* gw  = (which ? gnw_w : gnh_w) + g * GC_;
    const float* gb  = (which ? gnw_b : gnh_b) + g * GC_;

    const float* wsel; const float* bsel; int ks;
    switch (g) {
        case 0:  wsel = w3; bsel = b3; ks = 3; break;
        case 1:  wsel = w5; bsel = b5; ks = 5; break;
        case 2:  wsel = w7; bsel = b7; ks = 7; break;
        default: wsel = w9; bsel = b9; ks = 9; break;
    }

    __shared__ __align__(16) float lin[GC_ * HW_];   // 28 KB
    __shared__ float wl[GC_ * 9];
    __shared__ float bl[GC_];
    __shared__ float red[10];

    // vectorized stage: 7168 floats = 1792 float4
    {
        const floatx4* in4 = (const floatx4*)in;
        floatx4* lin4 = (floatx4*)lin;
        for (int i = t; i < GC_ * HW_ / 4; i += 256) lin4[i] = in4[i];
    }
    const int nw = GC_ * ks;
    for (int i = t; i < nw; i += 256) wl[i] = wsel[i];
    if (t < GC_) bl[t] = bsel[t];
    __syncthreads();

    const int k2 = ks >> 1;
    float acc[28];
    float s = 0.f, s2 = 0.f;
    #pragma unroll
    for (int k = 0; k < 28; k++) {
        int idx = t + k * 256;
        int c = idx / HW_, l = idx - c * HW_;
        float a = bl[c];
        for (int tt = 0; tt < ks; tt++) {
            int pos = l + tt - k2;
            if (pos >= 0 && pos < HW_) a += wl[c * ks + tt] * lin[c * HW_ + pos];
        }
        acc[k] = a;
        s += a; s2 += a * a;
    }
    #pragma unroll
    for (int o = 32; o > 0; o >>= 1) { s += __shfl_down(s, o); s2 += __shfl_down(s2, o); }
    int lane = t & 63, wid = t >> 6;
    if (lane == 0) { red[wid] = s; red[4 + wid] = s2; }
    __syncthreads();
    if (t == 0) {
        float S  = red[0] + red[1] + red[2] + red[3];
        float S2 = red[4] + red[5] + red[6] + red[7];
        float mean = S * (1.0f / (GC_ * HW_));
        float var  = S2 * (1.0f / (GC_ * HW_)) - mean * mean;
        red[8] = mean;
        red[9] = rsqrtf(var + EPS_);
    }
    __syncthreads();
    const float mean = red[8], rstd = red[9];

    #pragma unroll
    for (int k = 0; k < 28; k++) {
        int idx = t + k * 256;
        int c = idx / HW_;
        float v = (acc[k] - mean) * rstd * gw[c] + gb[c];
        out[idx] = 1.0f / (1.0f + expf(-v));
    }
}

// ---------------------------------------------------------------------------
// K3: per-(b,c): gated 7x7 avg-pool -> y; wave-reduced atomics into stats[b]
// ---------------------------------------------------------------------------
__global__ __launch_bounds__(256) void k_pool(const float* __restrict__ x,
                                              const float* __restrict__ ah,
                                              const float* __restrict__ aw,
                                              float* __restrict__ y,
                                              float* __restrict__ stats) {
    const int bc = blockIdx.x;
    const int t  = threadIdx.x;
    __shared__ float lds[PLANE];
    __shared__ float a_h[HW_];
    __shared__ float a_w[HW_];

    if (t < HW_) {
        a_h[t] = ah[(size_t)bc * HW_ + t];
        a_w[t] = aw[(size_t)bc * HW_ + t];
    }
    const floatx4* p4 = (const floatx4*)(x + (size_t)bc * PLANE);
    for (int f = t; f < PLANE4; f += 256) {
        floatx4 v = p4[f];
        int base = f * 4;
        lds[base]   = v.x; lds[base+1] = v.y;
        lds[base+2] = v.z; lds[base+3] = v.w;
    }
    __syncthreads();
    if (t < L2_) {   // threads 0..63 == wave 0
        int hh = t >> 3, ww = t & 7;
        float s = 0.f;
        #pragma unroll
        for (int i = 0; i < 7; i++) {
            float rsum = 0.f;
            int rbase = (7*hh + i) * HW_ + 7*ww;
            #pragma unroll
            for (int j = 0; j < 7; j++) rsum += lds[rbase + j] * a_w[7*ww + j];
            s += rsum * a_h[7*hh + i];
        }
        float ps = s * (1.0f / 49.0f);
        y[(size_t)bc * L2_ + t] = ps;
        // wave-reduce sum / sumsq of the 64 pooled values -> one atomic pair
        float a = ps, a2 = ps * ps;
        #pragma unroll
        for (int off = 32; off > 0; off >>= 1) {
            a  += __shfl_down(a, off);
            a2 += __shfl_down(a2, off);
        }
        if (t == 0) {
            int b = bc >> 9;   // bc / C_
            atomicAdd(&stats[b], a);
            atomicAdd(&stats[B_ + b], a2);
        }
    }
}

// ---------------------------------------------------------------------------
// K4: per (b, head): GN (stats precomputed) -> channel attention -> ca
// ---------------------------------------------------------------------------
__global__ __launch_bounds__(256) void k_attn(const float* __restrict__ y,
                                              const float* __restrict__ stats,
                                              const float* __restrict__ gn_w,
                                              const float* __restrict__ gn_b,
                                              const float* __restrict__ qw,
                                              const float* __restrict__ kw,
                                              const float* __restrict__ vw,
                                              float* __restrict__ ca) {
    const int blk = blockIdx.x;
    const int b = blk >> 3, h = blk & 7;
    const int t = threadIdx.x;

    __shared__ float yn[HD_ * 68];
    __shared__ float vbar[HD_];

    const float S  = stats[b];
    const float S2 = stats[B_ + b];
    const float mu   = S * (1.0f / (C_ * L2_));
    const float var  = S2 * (1.0f / (C_ * L2_)) - mu * mu;
    const float rstd = rsqrtf(var + EPS_);

    const floatx4* yp4 = (const floatx4*)(y + ((size_t)(b * C_ + h * HD_)) * L2_);
    for (int f = t; f < 1024; f += 256) {
        int d = f >> 4, lb = (f & 15) << 2;
        int ch = h * HD_ + d;
        float gsc = gn_w[ch] * rstd;
        float gof = gn_b[ch] - mu * gsc;
        floatx4 v = yp4[f];
        yn[d*68 + lb]   = v.x * gsc + gof;
        yn[d*68 + lb+1] = v.y * gsc + gof;
        yn[d*68 + lb+2] = v.z * gsc + gof;
        yn[d*68 + lb+3] = v.w * gsc + gof;
    }
    __syncthreads();

    if (t < HD_) {
        int ch = h * HD_ + t;
        float s = 0.f;
        #pragma unroll
        for (int l = 0; l < L2_; l++) s += yn[t*68 + l];
        vbar[t] = s * (1.0f / L2_) * vw[ch];
    }
    __syncthreads();

    const int d = t >> 2, eb = t & 3;
    const int ch0 = h * HD_;
    float acc[16];
    #pragma unroll
    for (int i = 0; i < 16; i++) acc[i] = 0.f;
    #pragma unroll 4
    for (int lb = 0; lb < 16; lb++) {
        floatx4 qv = *(const floatx4*)&yn[d*68 + lb*4];
        #pragma unroll
        for (int i = 0; i < 16; i++) {
            floatx4 kv = *(const floatx4*)&yn[(eb + 4*i)*68 + lb*4];
            acc[i] += qv.x*kv.x + qv.y*kv.y + qv.z*kv.z + qv.w*kv.w;
        }
    }
    const float qg = qw[ch0 + d] * 0.125f;
    float m = -1e30f;
    #pragma unroll
    for (int i = 0; i < 16; i++) {
        acc[i] *= qg * kw[ch0 + eb + 4*i];
        m = fmaxf(m, acc[i]);
    }
    m = fmaxf(m, __shfl_xor(m, 1));
    m = fmaxf(m, __shfl_xor(m, 2));
    float s1 = 0.f, s2 = 0.f;
    #pragma unroll
    for (int i = 0; i < 16; i++) {
        float p = expf(acc[i] - m);
        s1 += p;
        s2 += p * vbar[eb + 4*i];
    }
    s1 += __shfl_xor(s1, 1); s2 += __shfl_xor(s2, 1);
    s1 += __shfl_xor(s1, 2); s2 += __shfl_xor(s2, 2);
    if (eb == 0) {
        float o = s2 / s1;
        ca[(size_t)b * C_ + ch0 + d] = 1.0f / (1.0f + expf(-o));
    }
}

// ---------------------------------------------------------------------------
// K5: out = x * ah[h] * aw[w] * ca[b,c] — grid-stride streaming
// ---------------------------------------------------------------------------
__global__ __launch_bounds__(256) void k_out(const float* __restrict__ x,
                                             const float* __restrict__ ah,
                                             const float* __restrict__ aw,
                                             const float* __restrict__ ca,
                                             float* __restrict__ out) {
    const unsigned total4 = (unsigned)B_ * C_ * PLANE4;
    const unsigned stride = gridDim.x * blockDim.x;
    const floatx4* px = (const floatx4*)x;
    floatx4*       po = (floatx4*)out;

    for (unsigned i = blockIdx.x * blockDim.x + threadIdx.x; i < total4; i += stride) {
        unsigned bc = i / PLANE4;
        unsigned r  = i - bc * PLANE4;
        unsigned hh = r / 14;
        unsigned jb = (r - hh * 14) * 4;

        floatx4 v  = px[i];
        floatx4 w4 = *(const floatx4*)&aw[bc * HW_ + jb];
        float   m  = ca[bc] * ah[bc * HW_ + hh];
        v.x *= m * w4.x;
        v.y *= m * w4.y;
        v.z *= m * w4.z;
        v.w *= m * w4.w;
        __builtin_nontemporal_store(v, &po[i]);
    }
}

// ---------------------------------------------------------------------------
extern "C" void kernel_launch(void* const* d_in, const int* in_sizes, int n_in,
                              void* d_out, int out_size, void* d_ws, size_t ws_size,
                              hipStream_t stream) {
    const float* x     = (const float*)d_in[0];
    const float* w3    = (const float*)d_in[1];
    const float* b3    = (const float*)d_in[2];
    const float* w5    = (const float*)d_in[3];
    const float* b5    = (const float*)d_in[4];
    const float* w7    = (const float*)d_in[5];
    const float* b7    = (const float*)d_in[6];
    const float* w9    = (const float*)d_in[7];
    const float* b9    = (const float*)d_in[8];
    const float* gnh_w = (const float*)d_in[9];
    const float* gnh_b = (const float*)d_in[10];
    const float* gnw_w = (const float*)d_in[11];
    const float* gnw_b = (const float*)d_in[12];
    const float* gn_w  = (const float*)d_in[13];
    const float* gn_b  = (const float*)d_in[14];
    const float* qw    = (const float*)d_in[15];
    const float* kw    = (const float*)d_in[16];
    const float* vw    = (const float*)d_in[17];

    float* ws = (float*)d_ws;
    const size_t N_BC56 = (size_t)B_ * C_ * HW_;   // 917504
    float* xh    = ws;
    float* xw_   = xh + N_BC56;
    float* ah    = xw_ + N_BC56;
    float* aw    = ah + N_BC56;
    float* yy    = aw + N_BC56;                    // B*C*64 = 1048576
    float* stats = yy + (size_t)B_ * C_ * L2_;     // 64
    float* ca    = stats + 2 * B_;                 // 16384

    const int nbc = B_ * C_;   // 16384

    k_means<<<nbc, 256, 0, stream>>>(x, xh, xw_, stats);
    k_conv_gn_sig<<<B_ * 8, 256, 0, stream>>>(xh, xw_, w3, b3, w5, b5, w7, b7, w9, b9,
                                              gnh_w, gnh_b, gnw_w, gnw_b, ah, aw);
    k_pool<<<nbc, 256, 0, stream>>>(x, ah, aw, yy, stats);
    k_attn<<<B_ * 8, 256, 0, stream>>>(yy, stats, gn_w, gn_b, qw, kw, vw, ca);
    k_out<<<2048, 256, 0, stream>>>(x, ah, aw, ca, (float*)d_out);
}

// Round 7
// 170.123 us; speedup vs baseline: 3.0335x; 2.0523x over previous
//
#include <hip/hip_runtime.h>
#include <math.h>

// Problem constants
#define B_     32
#define C_     512
#define HW_    56
#define PLANE  3136
#define PLANE4 784
#define GC_    128
#define L2_    64
#define HD_    64
#define EPS_   1e-5f

typedef float floatx4 __attribute__((ext_vector_type(4)));
typedef float floatx2 __attribute__((ext_vector_type(2)));

// ---------------------------------------------------------------------------
// K1: per-(b,c) plane -> row means (over W) = x_h, col means (over H) = x_w
// ---------------------------------------------------------------------------
__global__ __launch_bounds__(256) void k_means(const float* __restrict__ x,
                                               float* __restrict__ xh,
                                               float* __restrict__ xw) {
    const int bc = blockIdx.x;
    const int t  = threadIdx.x;
    __shared__ float lds[PLANE];
    __shared__ float rp[224];
    __shared__ float cp[224];

    const floatx4* p4 = (const floatx4*)(x + (size_t)bc * PLANE);
    for (int f = t; f < PLANE4; f += 256) {
        floatx4 v = p4[f];
        int base = f * 4;
        lds[base]   = v.x; lds[base+1] = v.y;
        lds[base+2] = v.z; lds[base+3] = v.w;
    }
    __syncthreads();
    if (t < 224) {
        int r = t >> 2, q = t & 3;
        float s = 0.f;
        int base = r * HW_ + q * 14;
        #pragma unroll
        for (int i = 0; i < 14; i++) s += lds[base + i];
        rp[t] = s;
        float s2 = 0.f;
        int cbase = q * 14 * HW_ + r;
        #pragma unroll
        for (int i = 0; i < 14; i++) s2 += lds[cbase + i * HW_];
        cp[t] = s2;
    }
    __syncthreads();
    if (t < HW_) {
        float rs = rp[4*t] + rp[4*t+1] + rp[4*t+2] + rp[4*t+3];
        xh[(size_t)bc * HW_ + t] = rs * (1.0f / HW_);
        float cs = cp[4*t] + cp[4*t+1] + cp[4*t+2] + cp[4*t+3];
        xw[(size_t)bc * HW_ + t] = cs * (1.0f / HW_);
    }
}

// ---------------------------------------------------------------------------
// K2: per (b, group, {h|w}): depthwise conv1d + bias, GroupNorm, sigmoid
// ---------------------------------------------------------------------------
__global__ __launch_bounds__(256) void k_conv_gn_sig(
    const float* __restrict__ xh, const float* __restrict__ xw,
    const float* __restrict__ w3, const float* __restrict__ b3,
    const float* __restrict__ w5, const float* __restrict__ b5,
    const float* __restrict__ w7, const float* __restrict__ b7,
    const float* __restrict__ w9, const float* __restrict__ b9,
    const float* __restrict__ gnh_w, const float* __restrict__ gnh_b,
    const float* __restrict__ gnw_w, const float* __restrict__ gnw_b,
    float* __restrict__ ah, float* __restrict__ aw) {

    const int blk = blockIdx.x;
    const int b = blk >> 3;
    const int which = (blk & 7) >> 2;
    const int g = blk & 3;
    const int t = threadIdx.x;

    const float* in  = (which ? xw : xh) + ((size_t)(b * C_ + g * GC_)) * HW_;
    float*       out = (which ? aw : ah) + ((size_t)(b * C_ + g * GC_)) * HW_;
    const float* gw  = (which ? gnw_w : gnh_w) + g * GC_;
    const float* gb  = (which ? gnw_b : gnh_b) + g * GC_;

    const float* wsel; const float* bsel; int ks;
    switch (g) {
        case 0:  wsel = w3; bsel = b3; ks = 3; break;
        case 1:  wsel = w5; bsel = b5; ks = 5; break;
        case 2:  wsel = w7; bsel = b7; ks = 7; break;
        default: wsel = w9; bsel = b9; ks = 9; break;
    }

    __shared__ __align__(16) float lin[GC_ * HW_];   // 28 KB
    __shared__ float wl[GC_ * 9];
    __shared__ float bl[GC_];
    __shared__ float red[10];

    {
        const floatx4* in4 = (const floatx4*)in;
        floatx4* lin4 = (floatx4*)lin;
        for (int i = t; i < GC_ * HW_ / 4; i += 256) lin4[i] = in4[i];
    }
    const int nw = GC_ * ks;
    for (int i = t; i < nw; i += 256) wl[i] = wsel[i];
    if (t < GC_) bl[t] = bsel[t];
    __syncthreads();

    const int k2 = ks >> 1;
    float acc[28];
    float s = 0.f, s2 = 0.f;
    #pragma unroll
    for (int k = 0; k < 28; k++) {
        int idx = t + k * 256;
        int c = idx / HW_, l = idx - c * HW_;
        float a = bl[c];
        for (int tt = 0; tt < ks; tt++) {
            int pos = l + tt - k2;
            if (pos >= 0 && pos < HW_) a += wl[c * ks + tt] * lin[c * HW_ + pos];
        }
        acc[k] = a;
        s += a; s2 += a * a;
    }
    #pragma unroll
    for (int o = 32; o > 0; o >>= 1) { s += __shfl_down(s, o); s2 += __shfl_down(s2, o); }
    int lane = t & 63, wid = t >> 6;
    if (lane == 0) { red[wid] = s; red[4 + wid] = s2; }
    __syncthreads();
    if (t == 0) {
        float S  = red[0] + red[1] + red[2] + red[3];
        float S2 = red[4] + red[5] + red[6] + red[7];
        float mean = S * (1.0f / (GC_ * HW_));
        float var  = S2 * (1.0f / (GC_ * HW_)) - mean * mean;
        red[8] = mean;
        red[9] = rsqrtf(var + EPS_);
    }
    __syncthreads();
    const float mean = red[8], rstd = red[9];

    #pragma unroll
    for (int k = 0; k < 28; k++) {
        int idx = t + k * 256;
        int c = idx / HW_;
        float v = (acc[k] - mean) * rstd * gw[c] + gb[c];
        out[idx] = 1.0f / (1.0f + expf(-v));
    }
}

// ---------------------------------------------------------------------------
// K3: per-(b,c): gated 7x7 avg-pool -> y; per-block (sum,sumsq) -> psum[bc]
// (non-atomic; reduced later by K4)
// ---------------------------------------------------------------------------
__global__ __launch_bounds__(256) void k_pool(const float* __restrict__ x,
                                              const float* __restrict__ ah,
                                              const float* __restrict__ aw,
                                              float* __restrict__ y,
                                              floatx2* __restrict__ psum) {
    const int bc = blockIdx.x;
    const int t  = threadIdx.x;
    __shared__ float lds[PLANE];
    __shared__ float a_h[HW_];
    __shared__ float a_w[HW_];

    if (t < HW_) {
        a_h[t] = ah[(size_t)bc * HW_ + t];
        a_w[t] = aw[(size_t)bc * HW_ + t];
    }
    const floatx4* p4 = (const floatx4*)(x + (size_t)bc * PLANE);
    for (int f = t; f < PLANE4; f += 256) {
        floatx4 v = p4[f];
        int base = f * 4;
        lds[base]   = v.x; lds[base+1] = v.y;
        lds[base+2] = v.z; lds[base+3] = v.w;
    }
    __syncthreads();
    if (t < L2_) {   // threads 0..63 == wave 0
        int hh = t >> 3, ww = t & 7;
        float s = 0.f;
        #pragma unroll
        for (int i = 0; i < 7; i++) {
            float rsum = 0.f;
            int rbase = (7*hh + i) * HW_ + 7*ww;
            #pragma unroll
            for (int j = 0; j < 7; j++) rsum += lds[rbase + j] * a_w[7*ww + j];
            s += rsum * a_h[7*hh + i];
        }
        float ps = s * (1.0f / 49.0f);
        y[(size_t)bc * L2_ + t] = ps;
        float a = ps, a2 = ps * ps;
        #pragma unroll
        for (int off = 32; off > 0; off >>= 1) {
            a  += __shfl_down(a, off);
            a2 += __shfl_down(a2, off);
        }
        if (t == 0) {
            floatx2 pv; pv.x = a; pv.y = a2;
            psum[bc] = pv;
        }
    }
}

// ---------------------------------------------------------------------------
// K4: per (b, head): reduce psum[b*512..] -> GN stats; channel attention -> ca
// ---------------------------------------------------------------------------
__global__ __launch_bounds__(256) void k_attn(const float* __restrict__ y,
                                              const floatx2* __restrict__ psum,
                                              const float* __restrict__ gn_w,
                                              const float* __restrict__ gn_b,
                                              const float* __restrict__ qw,
                                              const float* __restrict__ kw,
                                              const float* __restrict__ vw,
                                              float* __restrict__ ca) {
    const int blk = blockIdx.x;
    const int b = blk >> 3, h = blk & 7;
    const int t = threadIdx.x;

    __shared__ float yn[HD_ * 68];
    __shared__ float vbar[HD_];
    __shared__ float red[10];

    // reduce 512 per-block partials for this batch (L2-hit, 4 KB)
    {
        floatx2 p0 = psum[b * C_ + t];
        floatx2 p1 = psum[b * C_ + 256 + t];
        float s  = p0.x + p1.x;
        float s2 = p0.y + p1.y;
        #pragma unroll
        for (int off = 32; off > 0; off >>= 1) {
            s  += __shfl_down(s, off);
            s2 += __shfl_down(s2, off);
        }
        int lane = t & 63, wid = t >> 6;
        if (lane == 0) { red[wid] = s; red[4 + wid] = s2; }
        __syncthreads();
        if (t == 0) {
            float S  = red[0] + red[1] + red[2] + red[3];
            float S2 = red[4] + red[5] + red[6] + red[7];
            float mean = S * (1.0f / (C_ * L2_));
            float var  = S2 * (1.0f / (C_ * L2_)) - mean * mean;
            red[8] = mean;
            red[9] = rsqrtf(var + EPS_);
        }
        __syncthreads();
    }
    const float mu = red[8], rstd = red[9];

    const floatx4* yp4 = (const floatx4*)(y + ((size_t)(b * C_ + h * HD_)) * L2_);
    for (int f = t; f < 1024; f += 256) {
        int d = f >> 4, lb = (f & 15) << 2;
        int ch = h * HD_ + d;
        float gsc = gn_w[ch] * rstd;
        float gof = gn_b[ch] - mu * gsc;
        floatx4 v = yp4[f];
        yn[d*68 + lb]   = v.x * gsc + gof;
        yn[d*68 + lb+1] = v.y * gsc + gof;
        yn[d*68 + lb+2] = v.z * gsc + gof;
        yn[d*68 + lb+3] = v.w * gsc + gof;
    }
    __syncthreads();

    if (t < HD_) {
        int ch = h * HD_ + t;
        float s = 0.f;
        #pragma unroll
        for (int l = 0; l < L2_; l++) s += yn[t*68 + l];
        vbar[t] = s * (1.0f / L2_) * vw[ch];
    }
    __syncthreads();

    const int d = t >> 2, eb = t & 3;
    const int ch0 = h * HD_;
    float acc[16];
    #pragma unroll
    for (int i = 0; i < 16; i++) acc[i] = 0.f;
    #pragma unroll 4
    for (int lb = 0; lb < 16; lb++) {
        floatx4 qv = *(const floatx4*)&yn[d*68 + lb*4];
        #pragma unroll
        for (int i = 0; i < 16; i++) {
            floatx4 kv = *(const floatx4*)&yn[(eb + 4*i)*68 + lb*4];
            acc[i] += qv.x*kv.x + qv.y*kv.y + qv.z*kv.z + qv.w*kv.w;
        }
    }
    const float qg = qw[ch0 + d] * 0.125f;
    float m = -1e30f;
    #pragma unroll
    for (int i = 0; i < 16; i++) {
        acc[i] *= qg * kw[ch0 + eb + 4*i];
        m = fmaxf(m, acc[i]);
    }
    m = fmaxf(m, __shfl_xor(m, 1));
    m = fmaxf(m, __shfl_xor(m, 2));
    float s1 = 0.f, s2 = 0.f;
    #pragma unroll
    for (int i = 0; i < 16; i++) {
        float p = expf(acc[i] - m);
        s1 += p;
        s2 += p * vbar[eb + 4*i];
    }
    s1 += __shfl_xor(s1, 1); s2 += __shfl_xor(s2, 1);
    s1 += __shfl_xor(s1, 2); s2 += __shfl_xor(s2, 2);
    if (eb == 0) {
        float o = s2 / s1;
        ca[(size_t)b * C_ + ch0 + d] = 1.0f / (1.0f + expf(-o));
    }
}

// ---------------------------------------------------------------------------
// K5: out = x * ah[h] * aw[w] * ca[b,c] — grid-stride streaming
// ---------------------------------------------------------------------------
__global__ __launch_bounds__(256) void k_out(const float* __restrict__ x,
                                             const float* __restrict__ ah,
                                             const float* __restrict__ aw,
                                             const float* __restrict__ ca,
                                             float* __restrict__ out) {
    const unsigned total4 = (unsigned)B_ * C_ * PLANE4;
    const unsigned stride = gridDim.x * blockDim.x;
    const floatx4* px = (const floatx4*)x;
    floatx4*       po = (floatx4*)out;

    for (unsigned i = blockIdx.x * blockDim.x + threadIdx.x; i < total4; i += stride) {
        unsigned bc = i / PLANE4;
        unsigned r  = i - bc * PLANE4;
        unsigned hh = r / 14;
        unsigned jb = (r - hh * 14) * 4;

        floatx4 v  = px[i];
        floatx4 w4 = *(const floatx4*)&aw[bc * HW_ + jb];
        float   m  = ca[bc] * ah[bc * HW_ + hh];
        v.x *= m * w4.x;
        v.y *= m * w4.y;
        v.z *= m * w4.z;
        v.w *= m * w4.w;
        __builtin_nontemporal_store(v, &po[i]);
    }
}

// ---------------------------------------------------------------------------
extern "C" void kernel_launch(void* const* d_in, const int* in_sizes, int n_in,
                              void* d_out, int out_size, void* d_ws, size_t ws_size,
                              hipStream_t stream) {
    const float* x     = (const float*)d_in[0];
    const float* w3    = (const float*)d_in[1];
    const float* b3    = (const float*)d_in[2];
    const float* w5    = (const float*)d_in[3];
    const float* b5    = (const float*)d_in[4];
    const float* w7    = (const float*)d_in[5];
    const float* b7    = (const float*)d_in[6];
    const float* w9    = (const float*)d_in[7];
    const float* b9    = (const float*)d_in[8];
    const float* gnh_w = (const float*)d_in[9];
    const float* gnh_b = (const float*)d_in[10];
    const float* gnw_w = (const float*)d_in[11];
    const float* gnw_b = (const float*)d_in[12];
    const float* gn_w  = (const float*)d_in[13];
    const float* gn_b  = (const float*)d_in[14];
    const float* qw    = (const float*)d_in[15];
    const float* kw    = (const float*)d_in[16];
    const float* vw    = (const float*)d_in[17];

    float* ws = (float*)d_ws;
    const size_t N_BC56 = (size_t)B_ * C_ * HW_;   // 917504
    float* xh    = ws;
    float* xw_   = xh + N_BC56;
    float* ah    = xw_ + N_BC56;
    float* aw    = ah + N_BC56;
    float* yy    = aw + N_BC56;                    // B*C*64 = 1048576
    float* ca    = yy + (size_t)B_ * C_ * L2_;     // 16384
    floatx2* psum = (floatx2*)(ca + (size_t)B_ * C_);  // 16384 float2

    const int nbc = B_ * C_;   // 16384

    k_means<<<nbc, 256, 0, stream>>>(x, xh, xw_);
    k_conv_gn_sig<<<B_ * 8, 256, 0, stream>>>(xh, xw_, w3, b3, w5, b5, w7, b7, w9, b9,
                                              gnh_w, gnh_b, gnw_w, gnw_b, ah, aw);
    k_pool<<<nbc, 256, 0, stream>>>(x, ah, aw, yy, psum);
    k_attn<<<B_ * 8, 256, 0, stream>>>(yy, psum, gn_w, gn_b, qw, kw, vw, ca);
    k_out<<<2048, 256, 0, stream>>>(x, ah, aw, ca, (float*)d_out);
}

// Round 8
// 146.995 us; speedup vs baseline: 3.5108x; 1.1573x over previous
//
#include <hip/hip_runtime.h>
#include <math.h>

// Problem constants
#define B_     32
#define C_     512
#define HW_    56
#define PLANE  3136
#define PLANE4 784
#define GC_    128
#define L2_    64
#define HD_    64
#define EPS_   1e-5f
#define NBC    (B_*C_)   // 16384

typedef float floatx4 __attribute__((ext_vector_type(4)));
typedef float floatx2 __attribute__((ext_vector_type(2)));

// ---------------------------------------------------------------------------
// K1: per-(b,c): row/col means -> depthwise conv (k per group) + bias ->
//     conv outputs ch/cw + per-channel (sum,sumsq) partials for the GN.
// ---------------------------------------------------------------------------
__global__ __launch_bounds__(256) void k_means_conv(
    const float* __restrict__ x,
    const float* __restrict__ w3, const float* __restrict__ b3,
    const float* __restrict__ w5, const float* __restrict__ b5,
    const float* __restrict__ w7, const float* __restrict__ b7,
    const float* __restrict__ w9, const float* __restrict__ b9,
    float* __restrict__ ch, float* __restrict__ cw,
    floatx2* __restrict__ pstat) {

    const int bc = blockIdx.x;
    const int t  = threadIdx.x;
    const int c  = bc & (C_ - 1);
    const int g  = c >> 7;          // group 0..3
    const int cc = c & (GC_ - 1);   // channel within group

    __shared__ float lds[PLANE];
    __shared__ float rp[224];
    __shared__ float cp[224];
    __shared__ float mh[HW_];
    __shared__ float mw[HW_];

    const floatx4* p4 = (const floatx4*)(x + (size_t)bc * PLANE);
    for (int f = t; f < PLANE4; f += 256) {
        floatx4 v = p4[f];
        int base = f * 4;
        lds[base]   = v.x; lds[base+1] = v.y;
        lds[base+2] = v.z; lds[base+3] = v.w;
    }
    __syncthreads();
    if (t < 224) {
        int r = t >> 2, q = t & 3;
        float s = 0.f;
        int base = r * HW_ + q * 14;
        #pragma unroll
        for (int i = 0; i < 14; i++) s += lds[base + i];
        rp[t] = s;
        float s2 = 0.f;
        int cbase = q * 14 * HW_ + r;
        #pragma unroll
        for (int i = 0; i < 14; i++) s2 += lds[cbase + i * HW_];
        cp[t] = s2;
    }
    __syncthreads();
    if (t < HW_) {
        mh[t] = (rp[4*t] + rp[4*t+1] + rp[4*t+2] + rp[4*t+3]) * (1.0f / HW_);
        mw[t] = (cp[4*t] + cp[4*t+1] + cp[4*t+2] + cp[4*t+3]) * (1.0f / HW_);
    }
    __syncthreads();

    // conv taps for this channel
    const float* wsel; const float* bsel; int ks;
    switch (g) {
        case 0:  wsel = w3; bsel = b3; ks = 3; break;
        case 1:  wsel = w5; bsel = b5; ks = 5; break;
        case 2:  wsel = w7; bsel = b7; ks = 7; break;
        default: wsel = w9; bsel = b9; ks = 9; break;
    }
    const int k2 = ks >> 1;
    const int lane = t & 63, wid = t >> 6;

    float cv = 0.f;
    bool valid = (wid < 2) && (lane < HW_);
    if (valid) {
        const float* m = (wid == 0) ? mh : mw;
        float a = bsel[cc];
        for (int tt = 0; tt < ks; tt++) {
            int pos = lane + tt - k2;
            if (pos >= 0 && pos < HW_) a += wsel[cc * ks + tt] * m[pos];
        }
        cv = a;
        float* o = (wid == 0) ? ch : cw;
        o[(size_t)bc * HW_ + lane] = a;
    }
    // wave-reduce (sum,sumsq) within waves 0 (h) and 1 (w)
    if (wid < 2) {
        float s = cv, s2 = cv * cv;
        #pragma unroll
        for (int off = 32; off > 0; off >>= 1) {
            s  += __shfl_down(s, off);
            s2 += __shfl_down(s2, off);
        }
        if (lane == 0) {
            floatx2 pv; pv.x = s; pv.y = s2;
            pstat[(size_t)wid * NBC + bc] = pv;
        }
    }
}

// ---------------------------------------------------------------------------
// K3: per-(b,c): reduce group GN stats (128 partials, L2-hit), gates =
//     sigmoid(GN(conv)) for h and w (written for K5), gated 7x7 pool -> y,
//     per-block (sum,sumsq) -> psum for K4.
// ---------------------------------------------------------------------------
__global__ __launch_bounds__(256) void k_pool(
    const float* __restrict__ x,
    const float* __restrict__ ch, const float* __restrict__ cw,
    const floatx2* __restrict__ pstat,
    const float* __restrict__ gnh_w, const float* __restrict__ gnh_b,
    const float* __restrict__ gnw_w, const float* __restrict__ gnw_b,
    float* __restrict__ ah, float* __restrict__ aw,
    float* __restrict__ y, floatx2* __restrict__ psum) {

    const int bc = blockIdx.x;
    const int t  = threadIdx.x;
    const int b  = bc >> 9;
    const int c  = bc & (C_ - 1);
    const int g  = c >> 7;
    const int gbase = b * C_ + g * GC_;   // first channel of this group

    __shared__ float lds[PLANE];
    __shared__ float a_h[HW_];
    __shared__ float a_w[HW_];
    __shared__ float red[4];

    const int lane = t & 63, wid = t >> 6;

    // prefetch group stats partials (wid 0: h-path, wid 1: w-path)
    float ps = 0.f, ps2 = 0.f;
    if (wid < 2) {
        const floatx2* P = pstat + (size_t)wid * NBC + gbase;
        floatx2 p0 = P[lane];
        floatx2 p1 = P[64 + lane];
        ps  = p0.x + p1.x;
        ps2 = p0.y + p1.y;
    }

    // stage plane
    const floatx4* p4 = (const floatx4*)(x + (size_t)bc * PLANE);
    for (int f = t; f < PLANE4; f += 256) {
        floatx4 v = p4[f];
        int base = f * 4;
        lds[base]   = v.x; lds[base+1] = v.y;
        lds[base+2] = v.z; lds[base+3] = v.w;
    }

    // reduce stats within waves 0/1
    if (wid < 2) {
        #pragma unroll
        for (int off = 32; off > 0; off >>= 1) {
            ps  += __shfl_down(ps, off);
            ps2 += __shfl_down(ps2, off);
        }
        if (lane == 0) { red[wid * 2] = ps; red[wid * 2 + 1] = ps2; }
    }
    __syncthreads();

    // gates
    {
        const float inv_n = 1.0f / (GC_ * HW_);
        if (wid == 0 && lane < HW_) {
            float mean = red[0] * inv_n;
            float var  = red[1] * inv_n - mean * mean;
            float rstd = rsqrtf(var + EPS_);
            float v = (ch[(size_t)bc * HW_ + lane] - mean) * rstd * gnh_w[c] + gnh_b[c];
            float gate = 1.0f / (1.0f + expf(-v));
            a_h[lane] = gate;
            ah[(size_t)bc * HW_ + lane] = gate;
        } else if (wid == 1 && lane < HW_) {
            float mean = red[2] * inv_n;
            float var  = red[3] * inv_n - mean * mean;
            float rstd = rsqrtf(var + EPS_);
            float v = (cw[(size_t)bc * HW_ + lane] - mean) * rstd * gnw_w[c] + gnw_b[c];
            float gate = 1.0f / (1.0f + expf(-v));
            a_w[lane] = gate;
            aw[(size_t)bc * HW_ + lane] = gate;
        }
    }
    __syncthreads();

    // gated 7x7 pool (wave 0)
    if (t < L2_) {
        int hh = t >> 3, ww = t & 7;
        float s = 0.f;
        #pragma unroll
        for (int i = 0; i < 7; i++) {
            float rsum = 0.f;
            int rbase = (7*hh + i) * HW_ + 7*ww;
            #pragma unroll
            for (int j = 0; j < 7; j++) rsum += lds[rbase + j] * a_w[7*ww + j];
            s += rsum * a_h[7*hh + i];
        }
        float pv = s * (1.0f / 49.0f);
        y[(size_t)bc * L2_ + t] = pv;
        float a = pv, a2 = pv * pv;
        #pragma unroll
        for (int off = 32; off > 0; off >>= 1) {
            a  += __shfl_down(a, off);
            a2 += __shfl_down(a2, off);
        }
        if (t == 0) {
            floatx2 q; q.x = a; q.y = a2;
            psum[bc] = q;
        }
    }
}

// ---------------------------------------------------------------------------
// K4: per (b, head): reduce psum -> GN stats; channel attention -> ca
// ---------------------------------------------------------------------------
__global__ __launch_bounds__(256) void k_attn(const float* __restrict__ y,
                                              const floatx2* __restrict__ psum,
                                              const float* __restrict__ gn_w,
                                              const float* __restrict__ gn_b,
                                              const float* __restrict__ qw,
                                              const float* __restrict__ kw,
                                              const float* __restrict__ vw,
                                              float* __restrict__ ca) {
    const int blk = blockIdx.x;
    const int b = blk >> 3, h = blk & 7;
    const int t = threadIdx.x;

    __shared__ float yn[HD_ * 68];
    __shared__ float vbar[HD_];
    __shared__ float red[10];

    {
        floatx2 p0 = psum[b * C_ + t];
        floatx2 p1 = psum[b * C_ + 256 + t];
        float s  = p0.x + p1.x;
        float s2 = p0.y + p1.y;
        #pragma unroll
        for (int off = 32; off > 0; off >>= 1) {
            s  += __shfl_down(s, off);
            s2 += __shfl_down(s2, off);
        }
        int lane = t & 63, wid = t >> 6;
        if (lane == 0) { red[wid] = s; red[4 + wid] = s2; }
        __syncthreads();
        if (t == 0) {
            float S  = red[0] + red[1] + red[2] + red[3];
            float S2 = red[4] + red[5] + red[6] + red[7];
            float mean = S * (1.0f / (C_ * L2_));
            float var  = S2 * (1.0f / (C_ * L2_)) - mean * mean;
            red[8] = mean;
            red[9] = rsqrtf(var + EPS_);
        }
        __syncthreads();
    }
    const float mu = red[8], rstd = red[9];

    const floatx4* yp4 = (const floatx4*)(y + ((size_t)(b * C_ + h * HD_)) * L2_);
    for (int f = t; f < 1024; f += 256) {
        int d = f >> 4, lb = (f & 15) << 2;
        int chn = h * HD_ + d;
        float gsc = gn_w[chn] * rstd;
        float gof = gn_b[chn] - mu * gsc;
        floatx4 v = yp4[f];
        yn[d*68 + lb]   = v.x * gsc + gof;
        yn[d*68 + lb+1] = v.y * gsc + gof;
        yn[d*68 + lb+2] = v.z * gsc + gof;
        yn[d*68 + lb+3] = v.w * gsc + gof;
    }
    __syncthreads();

    if (t < HD_) {
        int chn = h * HD_ + t;
        float s = 0.f;
        #pragma unroll
        for (int l = 0; l < L2_; l++) s += yn[t*68 + l];
        vbar[t] = s * (1.0f / L2_) * vw[chn];
    }
    __syncthreads();

    const int d = t >> 2, eb = t & 3;
    const int ch0 = h * HD_;
    float acc[16];
    #pragma unroll
    for (int i = 0; i < 16; i++) acc[i] = 0.f;
    #pragma unroll 4
    for (int lb = 0; lb < 16; lb++) {
        floatx4 qv = *(const floatx4*)&yn[d*68 + lb*4];
        #pragma unroll
        for (int i = 0; i < 16; i++) {
            floatx4 kv = *(const floatx4*)&yn[(eb + 4*i)*68 + lb*4];
            acc[i] += qv.x*kv.x + qv.y*kv.y + qv.z*kv.z + qv.w*kv.w;
        }
    }
    const float qg = qw[ch0 + d] * 0.125f;
    float m = -1e30f;
    #pragma unroll
    for (int i = 0; i < 16; i++) {
        acc[i] *= qg * kw[ch0 + eb + 4*i];
        m = fmaxf(m, acc[i]);
    }
    m = fmaxf(m, __shfl_xor(m, 1));
    m = fmaxf(m, __shfl_xor(m, 2));
    float s1 = 0.f, s2 = 0.f;
    #pragma unroll
    for (int i = 0; i < 16; i++) {
        float p = expf(acc[i] - m);
        s1 += p;
        s2 += p * vbar[eb + 4*i];
    }
    s1 += __shfl_xor(s1, 1); s2 += __shfl_xor(s2, 1);
    s1 += __shfl_xor(s1, 2); s2 += __shfl_xor(s2, 2);
    if (eb == 0) {
        float o = s2 / s1;
        ca[(size_t)b * C_ + ch0 + d] = 1.0f / (1.0f + expf(-o));
    }
}

// ---------------------------------------------------------------------------
// K5: out = x * ah[h] * aw[w] * ca[b,c] — grid-stride streaming
// ---------------------------------------------------------------------------
__global__ __launch_bounds__(256) void k_out(const float* __restrict__ x,
                                             const float* __restrict__ ah,
                                             const float* __restrict__ aw,
                                             const float* __restrict__ ca,
                                             float* __restrict__ out) {
    const unsigned total4 = (unsigned)B_ * C_ * PLANE4;
    const unsigned stride = gridDim.x * blockDim.x;
    const floatx4* px = (const floatx4*)x;
    floatx4*       po = (floatx4*)out;

    for (unsigned i = blockIdx.x * blockDim.x + threadIdx.x; i < total4; i += stride) {
        unsigned bc = i / PLANE4;
        unsigned r  = i - bc * PLANE4;
        unsigned hh = r / 14;
        unsigned jb = (r - hh * 14) * 4;

        floatx4 v  = px[i];
        floatx4 w4 = *(const floatx4*)&aw[bc * HW_ + jb];
        float   m  = ca[bc] * ah[bc * HW_ + hh];
        v.x *= m * w4.x;
        v.y *= m * w4.y;
        v.z *= m * w4.z;
        v.w *= m * w4.w;
        __builtin_nontemporal_store(v, &po[i]);
    }
}

// ---------------------------------------------------------------------------
extern "C" void kernel_launch(void* const* d_in, const int* in_sizes, int n_in,
                              void* d_out, int out_size, void* d_ws, size_t ws_size,
                              hipStream_t stream) {
    const float* x     = (const float*)d_in[0];
    const float* w3    = (const float*)d_in[1];
    const float* b3    = (const float*)d_in[2];
    const float* w5    = (const float*)d_in[3];
    const float* b5    = (const float*)d_in[4];
    const float* w7    = (const float*)d_in[5];
    const float* b7    = (const float*)d_in[6];
    const float* w9    = (const float*)d_in[7];
    const float* b9    = (const float*)d_in[8];
    const float* gnh_w = (const float*)d_in[9];
    const float* gnh_b = (const float*)d_in[10];
    const float* gnw_w = (const float*)d_in[11];
    const float* gnw_b = (const float*)d_in[12];
    const float* gn_w  = (const float*)d_in[13];
    const float* gn_b  = (const float*)d_in[14];
    const float* qw    = (const float*)d_in[15];
    const float* kw    = (const float*)d_in[16];
    const float* vw    = (const float*)d_in[17];

    float* ws = (float*)d_ws;
    const size_t N_BC56 = (size_t)B_ * C_ * HW_;        // 917504
    float* ch    = ws;                                   // conv-h outputs
    float* cw    = ch + N_BC56;                          // conv-w outputs
    float* ah    = cw + N_BC56;                          // gates h
    float* aw    = ah + N_BC56;                          // gates w
    float* yy    = aw + N_BC56;                          // B*C*64
    float* ca    = yy + (size_t)B_ * C_ * L2_;           // 16384
    floatx2* psum  = (floatx2*)(ca + (size_t)B_ * C_);   // 16384 float2
    floatx2* pstat = psum + NBC;                         // 2*16384 float2

    k_means_conv<<<NBC, 256, 0, stream>>>(x, w3, b3, w5, b5, w7, b7, w9, b9,
                                          ch, cw, pstat);
    k_pool<<<NBC, 256, 0, stream>>>(x, ch, cw, pstat,
                                    gnh_w, gnh_b, gnw_w, gnw_b,
                                    ah, aw, yy, psum);
    k_attn<<<B_ * 8, 256, 0, stream>>>(yy, psum, gn_w, gn_b, qw, kw, vw, ca);
    k_out<<<2048, 256, 0, stream>>>(x, ah, aw, ca, (float*)d_out);
}